// Round 1
// baseline (7639.861 us; speedup 1.0000x reference)
//
#include <hip/hip_runtime.h>

#define HID 512
#define OUTD 7
#define EPSV 1e-5f

// ---------------- setup kernels ----------------

__global__ void init_kernel(float* __restrict__ deg, float* __restrict__ gsum, int N) {
    int i = blockIdx.x * blockDim.x + threadIdx.x;
    if (i < N) deg[i] = 1.0f;          // self-loop contributes 1 to every in-degree
    if (i < HID) gsum[i] = 0.0f;
}

__global__ void deg_count(const int* __restrict__ dst, float* __restrict__ deg, int E) {
    int e = blockIdx.x * blockDim.x + threadIdx.x;
    if (e < E) atomicAdd(&deg[dst[e]], 1.0f);
}

__global__ void dinv_kernel(const float* __restrict__ deg, float* __restrict__ dinv, int N) {
    int i = blockIdx.x * blockDim.x + threadIdx.x;
    if (i < N) dinv[i] = rsqrtf(deg[i]);   // deg >= 1 always (self loop)
}

// ---------------- aggregation: ax = D^-1/2 (A+I) D^-1/2 x ----------------

// self-loop term: ax[i][j] = x[i][j] * dinv[i]^2   (also initializes ax)
__global__ void self_scale(const float* __restrict__ x, const float* __restrict__ dinv,
                           float* __restrict__ ax, int total4, int kshift) {
    int idx = blockIdx.x * blockDim.x + threadIdx.x;   // float4 index
    if (idx >= total4) return;
    int i = idx >> (kshift - 2);                       // row = (idx*4)/K
    float d = dinv[i]; d *= d;
    float4 v = ((const float4*)x)[idx];
    v.x *= d; v.y *= d; v.z *= d; v.w *= d;
    ((float4*)ax)[idx] = v;
}

// one wave per edge: ax[dst] += x[src] * dinv[src]*dinv[dst]
__global__ void edge_agg(const float* __restrict__ x, const int* __restrict__ src,
                         const int* __restrict__ dst, const float* __restrict__ dinv,
                         float* __restrict__ ax, int E, int K) {
    int gtid = blockIdx.x * blockDim.x + threadIdx.x;
    int e = gtid >> 6;
    int lane = gtid & 63;
    if (e >= E) return;
    int s = src[e], d = dst[e];
    float w = dinv[s] * dinv[d];
    const float4* xr = (const float4*)(x + (size_t)s * K);
    float* ar = ax + (size_t)d * K;
    int K4 = K >> 2;
    for (int j = lane; j < K4; j += 64) {
        float4 v = xr[j];
        atomicAdd(ar + 4*j + 0, v.x * w);
        atomicAdd(ar + 4*j + 1, v.y * w);
        atomicAdd(ar + 4*j + 2, v.z * w);
        atomicAdd(ar + 4*j + 3, v.w * w);
    }
}

// ---------------- GEMM: C[M x 512] = A[M x K] @ W[K x 512] + bias ----------------

#define BM 64
#define BN 128
#define TKK 16

__global__ __launch_bounds__(256) void gemm_bias(
        const float* __restrict__ A, const float* __restrict__ W,
        const float* __restrict__ bias, float* __restrict__ C, int M, int K) {
    __shared__ __align__(16) float As[TKK][BM + 4];   // transposed A tile, stride 68
    __shared__ __align__(16) float Bs[TKK][BN + 4];   // B tile, stride 132
    const int t  = threadIdx.x;
    const int m0 = blockIdx.y * BM;
    const int n0 = blockIdx.x * BN;
    const int tx = t & 15;          // -> 8 output cols
    const int ty = t >> 4;          // -> 4 output rows
    // A-load indexing: 64 rows x 16 k, one float4 (along k) per thread
    const int lam = t >> 2;
    const int lak = (t & 3) << 2;
    // B-load indexing: 16 rows x 128 cols, two float4 per thread
    const int lbk = t >> 4;
    const int lbn = (t & 15) << 3;

    float acc[4][8];
#pragma unroll
    for (int i = 0; i < 4; i++)
#pragma unroll
        for (int j = 0; j < 8; j++) acc[i][j] = 0.0f;

    const int gm_a = m0 + lam;
    for (int k0 = 0; k0 < K; k0 += TKK) {
        float4 av = make_float4(0.f, 0.f, 0.f, 0.f);
        if (gm_a < M) av = *(const float4*)(A + (size_t)gm_a * K + (k0 + lak));
        As[lak + 0][lam] = av.x;
        As[lak + 1][lam] = av.y;
        As[lak + 2][lam] = av.z;
        As[lak + 3][lam] = av.w;
        const float* wr = W + (size_t)(k0 + lbk) * HID + (n0 + lbn);
        *(float4*)&Bs[lbk][lbn]     = *(const float4*)wr;
        *(float4*)&Bs[lbk][lbn + 4] = *(const float4*)(wr + 4);
        __syncthreads();
#pragma unroll
        for (int kk = 0; kk < TKK; kk++) {
            float4 a  = *(const float4*)&As[kk][ty << 2];
            float4 b0 = *(const float4*)&Bs[kk][tx << 3];
            float4 b1 = *(const float4*)&Bs[kk][(tx << 3) + 4];
            float am[4] = {a.x, a.y, a.z, a.w};
            float bn[8] = {b0.x, b0.y, b0.z, b0.w, b1.x, b1.y, b1.z, b1.w};
#pragma unroll
            for (int i = 0; i < 4; i++)
#pragma unroll
                for (int j = 0; j < 8; j++)
                    acc[i][j] = fmaf(am[i], bn[j], acc[i][j]);
        }
        __syncthreads();
    }
#pragma unroll
    for (int i = 0; i < 4; i++) {
        int gm = m0 + (ty << 2) + i;
        if (gm >= M) continue;
        float* cr = C + (size_t)gm * HID + n0 + (tx << 3);
        const float* br = bias + n0 + (tx << 3);
        float4 o0 = make_float4(acc[i][0] + br[0], acc[i][1] + br[1],
                                acc[i][2] + br[2], acc[i][3] + br[3]);
        float4 o1 = make_float4(acc[i][4] + br[4], acc[i][5] + br[5],
                                acc[i][6] + br[6], acc[i][7] + br[7]);
        *(float4*)cr       = o0;
        *(float4*)(cr + 4) = o1;
    }
}

// ---------------- LayerNorm + ReLU (wave per row, H=512) ----------------

__global__ void ln_relu(float* __restrict__ h, const float* __restrict__ gamma,
                        const float* __restrict__ beta, int N) {
    int gtid = blockIdx.x * blockDim.x + threadIdx.x;
    int r = gtid >> 6, lane = gtid & 63;
    if (r >= N) return;
    float* row = h + (size_t)r * HID;
    float4 v0 = ((const float4*)row)[lane];        // cols [0,256)
    float4 v1 = ((const float4*)row)[lane + 64];   // cols [256,512)
    float s = v0.x + v0.y + v0.z + v0.w + v1.x + v1.y + v1.z + v1.w;
    float q = v0.x*v0.x + v0.y*v0.y + v0.z*v0.z + v0.w*v0.w
            + v1.x*v1.x + v1.y*v1.y + v1.z*v1.z + v1.w*v1.w;
#pragma unroll
    for (int off = 32; off > 0; off >>= 1) {
        s += __shfl_xor(s, off);
        q += __shfl_xor(q, off);
    }
    float mu  = s * (1.0f / HID);
    float var = q * (1.0f / HID) - mu * mu;
    float rs  = rsqrtf(var + EPSV);
    float4 g0 = ((const float4*)gamma)[lane], g1 = ((const float4*)gamma)[lane + 64];
    float4 b0 = ((const float4*)beta)[lane],  b1 = ((const float4*)beta)[lane + 64];
    v0.x = fmaxf((v0.x - mu) * rs * g0.x + b0.x, 0.f);
    v0.y = fmaxf((v0.y - mu) * rs * g0.y + b0.y, 0.f);
    v0.z = fmaxf((v0.z - mu) * rs * g0.z + b0.z, 0.f);
    v0.w = fmaxf((v0.w - mu) * rs * g0.w + b0.w, 0.f);
    v1.x = fmaxf((v1.x - mu) * rs * g1.x + b1.x, 0.f);
    v1.y = fmaxf((v1.y - mu) * rs * g1.y + b1.y, 0.f);
    v1.z = fmaxf((v1.z - mu) * rs * g1.z + b1.z, 0.f);
    v1.w = fmaxf((v1.w - mu) * rs * g1.w + b1.w, 0.f);
    ((float4*)row)[lane]      = v0;
    ((float4*)row)[lane + 64] = v1;
}

// ---------------- mean pool + output head ----------------

__global__ void colsum(const float* __restrict__ h, float* __restrict__ gsum, int N) {
    int t = threadIdx.x;   // 256
    float a0 = 0.f, a1 = 0.f;
    for (int r = blockIdx.x; r < N; r += gridDim.x) {
        const float* row = h + (size_t)r * HID;
        a0 += row[t];
        a1 += row[t + 256];
    }
    atomicAdd(&gsum[t], a0);
    atomicAdd(&gsum[t + 256], a1);
}

__global__ void out_kernel(const float* __restrict__ gsum, const float* __restrict__ Wout,
                           const float* __restrict__ bout, float* __restrict__ out, int N) {
    __shared__ float red[256];
    int t = threadIdx.x;
    float g0 = gsum[t], g1 = gsum[t + 256];
    float invn = 1.0f / (float)N;
    for (int o = 0; o < OUTD; o++) {
        float p = g0 * Wout[t * OUTD + o] + g1 * Wout[(t + 256) * OUTD + o];
        red[t] = p;
        __syncthreads();
        for (int sft = 128; sft > 0; sft >>= 1) {
            if (t < sft) red[t] += red[t + sft];
            __syncthreads();
        }
        if (t == 0) out[o] = red[0] * invn + bout[o];
        __syncthreads();
    }
}

// ---------------- launch ----------------

extern "C" void kernel_launch(void* const* d_in, const int* in_sizes, int n_in,
                              void* d_out, int out_size, void* d_ws, size_t ws_size,
                              hipStream_t stream) {
    const float* x  = (const float*)d_in[0];
    const int*   ei = (const int*)d_in[1];
    const int N = in_sizes[0] / 128;
    const int E = in_sizes[1] / 2;
    const int* src = ei;
    const int* dst = ei + E;
    const float* Ws[4] = {(const float*)d_in[2], (const float*)d_in[4],
                          (const float*)d_in[6], (const float*)d_in[8]};
    const float* bs[4] = {(const float*)d_in[3], (const float*)d_in[5],
                          (const float*)d_in[7], (const float*)d_in[9]};
    const float* gamma = (const float*)d_in[10];
    const float* beta  = (const float*)d_in[11];
    const float* Wout  = (const float*)d_in[12];
    const float* bout  = (const float*)d_in[13];
    float* out = (float*)d_out;

    float* ws   = (float*)d_ws;
    float* deg  = ws;
    float* dinv = ws + N;
    float* gsum = ws + 2 * N;
    float* ax   = ws + 2 * N + HID;              // N*512 fp32 (layer1 uses N*128)
    float* hbuf = ax + (size_t)N * HID;          // N*512 fp32

    init_kernel<<<(N + 255) / 256, 256, 0, stream>>>(deg, gsum, N);
    deg_count<<<(E + 255) / 256, 256, 0, stream>>>(dst, deg, E);
    dinv_kernel<<<(N + 255) / 256, 256, 0, stream>>>(deg, dinv, N);

    const float* xin = x;
    for (int l = 0; l < 4; l++) {
        const int K = (l == 0) ? 128 : HID;
        const int kshift = (l == 0) ? 7 : 9;
        const int total4 = N * K / 4;
        // ax = (A_hat) xin  — aggregate BEFORE the GEMM (A_hat(xW) == (A_hat x)W)
        self_scale<<<(total4 + 255) / 256, 256, 0, stream>>>(xin, dinv, ax, total4, kshift);
        edge_agg<<<E / 4, 256, 0, stream>>>(xin, src, dst, dinv, ax, E, K);
        // hbuf = ax @ W + b
        dim3 gg(HID / BN, (N + BM - 1) / BM);
        gemm_bias<<<gg, 256, 0, stream>>>(ax, Ws[l], bs[l], hbuf, N, K);
        // in-place LN + ReLU
        ln_relu<<<(N * 64 + 255) / 256, 256, 0, stream>>>(hbuf, gamma, beta, N);
        xin = hbuf;
    }
    colsum<<<512, 256, 0, stream>>>(hbuf, gsum, N);
    out_kernel<<<1, 256, 0, stream>>>(gsum, Wout, bout, out, N);
}

// Round 2
// 1031.899 us; speedup vs baseline: 7.4037x; 7.4037x over previous
//
#include <hip/hip_runtime.h>

#define HID 512
#define OUTD 7
#define EPSV 1e-5f
#define SCAN_T 1024

// ---------------- float4 helpers ----------------
__device__ __forceinline__ float4 f4fma(float4 v, float w, float4 a) {
    a.x = fmaf(v.x, w, a.x); a.y = fmaf(v.y, w, a.y);
    a.z = fmaf(v.z, w, a.z); a.w = fmaf(v.w, w, a.w);
    return a;
}
__device__ __forceinline__ float4 f4scale(float4 v, float w) {
    v.x *= w; v.y *= w; v.z *= w; v.w *= w; return v;
}

// ---------------- setup: degree, dinv, CSR ----------------

__global__ void zero_init(int* __restrict__ deg, float* __restrict__ gsum, int N) {
    int i = blockIdx.x * blockDim.x + threadIdx.x;
    if (i < N) deg[i] = 0;
    if (i < HID) gsum[i] = 0.0f;
}

__global__ void deg_count(const int* __restrict__ dst, int* __restrict__ deg, int E) {
    int e = blockIdx.x * blockDim.x + threadIdx.x;
    if (e < E) atomicAdd(&deg[dst[e]], 1);
}

__global__ void dinv_kernel(const int* __restrict__ deg, float* __restrict__ dinv, int N) {
    int i = blockIdx.x * blockDim.x + threadIdx.x;
    if (i < N) dinv[i] = rsqrtf((float)(deg[i] + 1));   // +1 self loop
}

// single-block exclusive scan: off[0..N], cursor = copy of off
__global__ void scan_kernel(const int* __restrict__ deg, int* __restrict__ off,
                            int* __restrict__ cursor, int N) {
    __shared__ int sums[SCAN_T];
    const int t = threadIdx.x;
    const int chunk = (N + SCAN_T - 1) / SCAN_T;
    const int b = t * chunk;
    const int e = min(b + chunk, N);
    int s = 0;
    for (int i = b; i < e; i++) s += deg[i];
    sums[t] = s;
    __syncthreads();
    for (int ofs = 1; ofs < SCAN_T; ofs <<= 1) {
        int v = 0;
        if (t >= ofs) v = sums[t - ofs];
        __syncthreads();
        sums[t] += v;
        __syncthreads();
    }
    int excl = (t == 0) ? 0 : sums[t - 1];
    for (int i = b; i < e; i++) {
        off[i] = excl; cursor[i] = excl; excl += deg[i];
    }
    if (b < N && e == N) off[N] = excl;
}

__global__ void fill_csr(const int* __restrict__ src, const int* __restrict__ dst,
                         int* __restrict__ cursor, int* __restrict__ srcs, int E) {
    int e = blockIdx.x * blockDim.x + threadIdx.x;
    if (e < E) {
        int p = atomicAdd(&cursor[dst[e]], 1);
        srcs[p] = src[e];
    }
}

// ---------------- aggregation (gather via CSR): one wave per dst row ----------------
// ax[r] = dinv[r] * ( x[r]*dinv[r] + sum_{e in row r} x[srcs[e]]*dinv[srcs[e]] )
__global__ void csr_agg(const float* __restrict__ x, const int* __restrict__ off,
                        const int* __restrict__ srcs, const float* __restrict__ dinv,
                        float* __restrict__ ax, int N, int K4) {
    int gtid = blockIdx.x * blockDim.x + threadIdx.x;
    int r = gtid >> 6, lane = gtid & 63;
    if (r >= N) return;
    const bool p0 = lane < K4;
    const bool p1 = lane + 64 < K4;
    const float dr = dinv[r];
    const float4* xr = (const float4*)x + (size_t)r * K4;
    float4 a0 = make_float4(0.f, 0.f, 0.f, 0.f), a1 = a0;
    if (p0) a0 = f4scale(xr[lane], dr);
    if (p1) a1 = f4scale(xr[lane + 64], dr);
    const int e1 = off[r + 1];
    for (int e = off[r]; e < e1; e++) {
        int s = srcs[e];
        float w = dinv[s];
        const float4* sr = (const float4*)x + (size_t)s * K4;
        if (p0) a0 = f4fma(sr[lane], w, a0);
        if (p1) a1 = f4fma(sr[lane + 64], w, a1);
    }
    float4* outr = (float4*)ax + (size_t)r * K4;
    if (p0) outr[lane] = f4scale(a0, dr);
    if (p1) outr[lane + 64] = f4scale(a1, dr);
}

// ---------------- GEMM: C[M x 512] = A[M x K] @ W[K x 512] + bias ----------------

#define BM 64
#define BN 128
#define TKK 16

__global__ __launch_bounds__(256) void gemm_bias(
        const float* __restrict__ A, const float* __restrict__ W,
        const float* __restrict__ bias, float* __restrict__ C, int M, int K) {
    __shared__ __align__(16) float As[TKK][BM + 4];
    __shared__ __align__(16) float Bs[TKK][BN + 4];
    const int t  = threadIdx.x;
    const int m0 = blockIdx.y * BM;
    const int n0 = blockIdx.x * BN;
    const int tx = t & 15;
    const int ty = t >> 4;
    const int lam = t >> 2;
    const int lak = (t & 3) << 2;
    const int lbk = t >> 4;
    const int lbn = (t & 15) << 3;

    float acc[4][8];
#pragma unroll
    for (int i = 0; i < 4; i++)
#pragma unroll
        for (int j = 0; j < 8; j++) acc[i][j] = 0.0f;

    const int gm_a = m0 + lam;
    for (int k0 = 0; k0 < K; k0 += TKK) {
        float4 av = make_float4(0.f, 0.f, 0.f, 0.f);
        if (gm_a < M) av = *(const float4*)(A + (size_t)gm_a * K + (k0 + lak));
        As[lak + 0][lam] = av.x;
        As[lak + 1][lam] = av.y;
        As[lak + 2][lam] = av.z;
        As[lak + 3][lam] = av.w;
        const float* wr = W + (size_t)(k0 + lbk) * HID + (n0 + lbn);
        *(float4*)&Bs[lbk][lbn]     = *(const float4*)wr;
        *(float4*)&Bs[lbk][lbn + 4] = *(const float4*)(wr + 4);
        __syncthreads();
#pragma unroll
        for (int kk = 0; kk < TKK; kk++) {
            float4 a  = *(const float4*)&As[kk][ty << 2];
            float4 b0 = *(const float4*)&Bs[kk][tx << 3];
            float4 b1 = *(const float4*)&Bs[kk][(tx << 3) + 4];
            float am[4] = {a.x, a.y, a.z, a.w};
            float bn[8] = {b0.x, b0.y, b0.z, b0.w, b1.x, b1.y, b1.z, b1.w};
#pragma unroll
            for (int i = 0; i < 4; i++)
#pragma unroll
                for (int j = 0; j < 8; j++)
                    acc[i][j] = fmaf(am[i], bn[j], acc[i][j]);
        }
        __syncthreads();
    }
#pragma unroll
    for (int i = 0; i < 4; i++) {
        int gm = m0 + (ty << 2) + i;
        if (gm >= M) continue;
        float* cr = C + (size_t)gm * HID + n0 + (tx << 3);
        const float* br = bias + n0 + (tx << 3);
        float4 o0 = make_float4(acc[i][0] + br[0], acc[i][1] + br[1],
                                acc[i][2] + br[2], acc[i][3] + br[3]);
        float4 o1 = make_float4(acc[i][4] + br[4], acc[i][5] + br[5],
                                acc[i][6] + br[6], acc[i][7] + br[7]);
        *(float4*)cr       = o0;
        *(float4*)(cr + 4) = o1;
    }
}

// ---------------- LayerNorm + ReLU (wave per row, H=512) ----------------

__global__ void ln_relu(float* __restrict__ h, const float* __restrict__ gamma,
                        const float* __restrict__ beta, int N) {
    int gtid = blockIdx.x * blockDim.x + threadIdx.x;
    int r = gtid >> 6, lane = gtid & 63;
    if (r >= N) return;
    float* row = h + (size_t)r * HID;
    float4 v0 = ((const float4*)row)[lane];
    float4 v1 = ((const float4*)row)[lane + 64];
    float s = v0.x + v0.y + v0.z + v0.w + v1.x + v1.y + v1.z + v1.w;
    float q = v0.x*v0.x + v0.y*v0.y + v0.z*v0.z + v0.w*v0.w
            + v1.x*v1.x + v1.y*v1.y + v1.z*v1.z + v1.w*v1.w;
#pragma unroll
    for (int off = 32; off > 0; off >>= 1) {
        s += __shfl_xor(s, off);
        q += __shfl_xor(q, off);
    }
    float mu  = s * (1.0f / HID);
    float var = q * (1.0f / HID) - mu * mu;
    float rs  = rsqrtf(var + EPSV);
    float4 g0 = ((const float4*)gamma)[lane], g1 = ((const float4*)gamma)[lane + 64];
    float4 b0 = ((const float4*)beta)[lane],  b1 = ((const float4*)beta)[lane + 64];
    v0.x = fmaxf((v0.x - mu) * rs * g0.x + b0.x, 0.f);
    v0.y = fmaxf((v0.y - mu) * rs * g0.y + b0.y, 0.f);
    v0.z = fmaxf((v0.z - mu) * rs * g0.z + b0.z, 0.f);
    v0.w = fmaxf((v0.w - mu) * rs * g0.w + b0.w, 0.f);
    v1.x = fmaxf((v1.x - mu) * rs * g1.x + b1.x, 0.f);
    v1.y = fmaxf((v1.y - mu) * rs * g1.y + b1.y, 0.f);
    v1.z = fmaxf((v1.z - mu) * rs * g1.z + b1.z, 0.f);
    v1.w = fmaxf((v1.w - mu) * rs * g1.w + b1.w, 0.f);
    ((float4*)row)[lane]      = v0;
    ((float4*)row)[lane + 64] = v1;
}

// ---------------- mean pool + output head ----------------

__global__ void colsum(const float* __restrict__ h, float* __restrict__ gsum, int N) {
    int t = threadIdx.x;   // 256
    float a0 = 0.f, a1 = 0.f;
    for (int r = blockIdx.x; r < N; r += gridDim.x) {
        const float* row = h + (size_t)r * HID;
        a0 += row[t];
        a1 += row[t + 256];
    }
    atomicAdd(&gsum[t], a0);
    atomicAdd(&gsum[t + 256], a1);
}

__global__ void out_kernel(const float* __restrict__ gsum, const float* __restrict__ Wout,
                           const float* __restrict__ bout, float* __restrict__ out, int N) {
    __shared__ float red[256];
    int t = threadIdx.x;
    float g0 = gsum[t], g1 = gsum[t + 256];
    float invn = 1.0f / (float)N;
    for (int o = 0; o < OUTD; o++) {
        float p = g0 * Wout[t * OUTD + o] + g1 * Wout[(t + 256) * OUTD + o];
        red[t] = p;
        __syncthreads();
        for (int sft = 128; sft > 0; sft >>= 1) {
            if (t < sft) red[t] += red[t + sft];
            __syncthreads();
        }
        if (t == 0) out[o] = red[0] * invn + bout[o];
        __syncthreads();
    }
}

// ---------------- launch ----------------

extern "C" void kernel_launch(void* const* d_in, const int* in_sizes, int n_in,
                              void* d_out, int out_size, void* d_ws, size_t ws_size,
                              hipStream_t stream) {
    const float* x  = (const float*)d_in[0];
    const int*   ei = (const int*)d_in[1];
    const int N = in_sizes[0] / 128;
    const int E = in_sizes[1] / 2;
    const int* src = ei;
    const int* dst = ei + E;
    const float* Ws[4] = {(const float*)d_in[2], (const float*)d_in[4],
                          (const float*)d_in[6], (const float*)d_in[8]};
    const float* bs[4] = {(const float*)d_in[3], (const float*)d_in[5],
                          (const float*)d_in[7], (const float*)d_in[9]};
    const float* gamma = (const float*)d_in[10];
    const float* beta  = (const float*)d_in[11];
    const float* Wout  = (const float*)d_in[12];
    const float* bout  = (const float*)d_in[13];
    float* out = (float*)d_out;

    // workspace layout
    char* p = (char*)d_ws;
    int* deg    = (int*)p;              p += sizeof(int) * N;
    int* off    = (int*)p;              p += sizeof(int) * (N + 1);
    int* cursor = (int*)p;              p += sizeof(int) * N;
    int* srcs   = (int*)p;              p += sizeof(int) * E;
    float* dinv = (float*)p;            p += sizeof(float) * N;
    float* gsum = (float*)p;            p += sizeof(float) * HID;
    float* ax   = (float*)p;            p += sizeof(float) * (size_t)N * HID;
    float* hbuf = (float*)p;            // N*HID floats

    // ---- CSR build (once, reused by all 4 layers) ----
    zero_init<<<(N + 255) / 256, 256, 0, stream>>>(deg, gsum, N);
    deg_count<<<(E + 255) / 256, 256, 0, stream>>>(dst, deg, E);
    scan_kernel<<<1, SCAN_T, 0, stream>>>(deg, off, cursor, N);
    dinv_kernel<<<(N + 255) / 256, 256, 0, stream>>>(deg, dinv, N);
    fill_csr<<<(E + 255) / 256, 256, 0, stream>>>(src, dst, cursor, srcs, E);

    const float* xin = x;
    for (int l = 0; l < 4; l++) {
        const int K = (l == 0) ? 128 : HID;
        const int K4 = K >> 2;
        // ax = A_hat @ xin (gather, no atomics)
        csr_agg<<<(N * 64 + 255) / 256, 256, 0, stream>>>(xin, off, srcs, dinv, ax, N, K4);
        // hbuf = ax @ W + b
        dim3 gg(HID / BN, (N + BM - 1) / BM);
        gemm_bias<<<gg, 256, 0, stream>>>(ax, Ws[l], bs[l], hbuf, N, K);
        // in-place LN + ReLU
        ln_relu<<<(N * 64 + 255) / 256, 256, 0, stream>>>(hbuf, gamma, beta, N);
        xin = hbuf;
    }
    colsum<<<512, 256, 0, stream>>>(hbuf, gsum, N);
    out_kernel<<<1, 256, 0, stream>>>(gsum, Wout, bout, out, N);
}

// Round 3
// 527.698 us; speedup vs baseline: 14.4777x; 1.9555x over previous
//
#include <hip/hip_runtime.h>

#define HID 512
#define OUTD 7
#define EPSV 1e-5f
#define SCAN_T 1024

typedef __attribute__((ext_vector_type(8))) short bf16x8;
typedef __attribute__((ext_vector_type(4))) float f32x4;
typedef unsigned short ushort_t;
typedef unsigned int uint_t;

// ---------------- bf16 helpers ----------------
__device__ __forceinline__ ushort_t f2bf(float f) {
    uint_t u = __float_as_uint(f);
    u = (u + 0x7fffu + ((u >> 16) & 1u)) >> 16;    // RNE
    return (ushort_t)u;
}
__device__ __forceinline__ float bflo(uint_t u) { return __uint_as_float(u << 16); }
__device__ __forceinline__ float bfhi(uint_t u) { return __uint_as_float(u & 0xffff0000u); }

// ---------------- setup: degree, dinv, CSR ----------------

__global__ void zero_init(int* __restrict__ deg, float* __restrict__ gsum, int N) {
    int i = blockIdx.x * blockDim.x + threadIdx.x;
    if (i < N) deg[i] = 0;
    if (i < HID) gsum[i] = 0.0f;
}

__global__ void deg_count(const int* __restrict__ dst, int* __restrict__ deg, int E) {
    int e = blockIdx.x * blockDim.x + threadIdx.x;
    if (e < E) atomicAdd(&deg[dst[e]], 1);
}

__global__ void dinv_kernel(const int* __restrict__ deg, float* __restrict__ dinv, int N) {
    int i = blockIdx.x * blockDim.x + threadIdx.x;
    if (i < N) dinv[i] = rsqrtf((float)(deg[i] + 1));   // +1 self loop
}

__global__ void scan_kernel(const int* __restrict__ deg, int* __restrict__ off,
                            int* __restrict__ cursor, int N) {
    __shared__ int sums[SCAN_T];
    const int t = threadIdx.x;
    const int chunk = (N + SCAN_T - 1) / SCAN_T;
    const int b = t * chunk;
    const int e = min(b + chunk, N);
    int s = 0;
    for (int i = b; i < e; i++) s += deg[i];
    sums[t] = s;
    __syncthreads();
    for (int ofs = 1; ofs < SCAN_T; ofs <<= 1) {
        int v = 0;
        if (t >= ofs) v = sums[t - ofs];
        __syncthreads();
        sums[t] += v;
        __syncthreads();
    }
    int excl = (t == 0) ? 0 : sums[t - 1];
    for (int i = b; i < e; i++) {
        off[i] = excl; cursor[i] = excl; excl += deg[i];
    }
    if (b < N && e == N) off[N] = excl;
}

__global__ void fill_csr(const int* __restrict__ src, const int* __restrict__ dst,
                         int* __restrict__ cursor, int* __restrict__ srcs, int E) {
    int e = blockIdx.x * blockDim.x + threadIdx.x;
    if (e < E) {
        int p = atomicAdd(&cursor[dst[e]], 1);
        srcs[p] = src[e];
    }
}

// ---------------- fp32 -> bf16 conversions ----------------

__global__ void cvt_x_bf16(const float* __restrict__ x, ushort_t* __restrict__ xb, int total) {
    int i = blockIdx.x * blockDim.x + threadIdx.x;
    if (i < total) xb[i] = f2bf(x[i]);
}

// W [K][512] row-major -> Wt [512][K] bf16
__global__ void cvt_w_bf16(const float* __restrict__ W, ushort_t* __restrict__ Wt, int K) {
    int i = blockIdx.x * blockDim.x + threadIdx.x;
    if (i >= K * HID) return;
    int k = i / HID, n = i % HID;
    Wt[(size_t)n * K + k] = f2bf(W[i]);
}

// ---------------- aggregation (gather via CSR), bf16 in/out, fp32 accum ----------------
// LPRS: log2(lanes per row). K = (1<<LPRS)*8. Each lane holds one uint4 (8 bf16).
template<int LPRS>
__global__ void csr_agg_bf16(const ushort_t* __restrict__ x, const int* __restrict__ off,
                             const int* __restrict__ srcs, const float* __restrict__ dinv,
                             ushort_t* __restrict__ ax, int N) {
    const int LPR = 1 << LPRS;
    const int K = LPR * 8;
    int gtid = blockIdx.x * blockDim.x + threadIdx.x;
    int wave = gtid >> 6, lane = gtid & 63;
    int sub = lane >> LPRS;
    int lr = lane & (LPR - 1);
    int r = wave * (64 >> LPRS) + sub;
    if (r >= N) return;
    const float dr = dinv[r];
    float a[8];
    {
        uint4 v = ((const uint4*)(x + (size_t)r * K))[lr];
        a[0] = bflo(v.x) * dr; a[1] = bfhi(v.x) * dr;
        a[2] = bflo(v.y) * dr; a[3] = bfhi(v.y) * dr;
        a[4] = bflo(v.z) * dr; a[5] = bfhi(v.z) * dr;
        a[6] = bflo(v.w) * dr; a[7] = bfhi(v.w) * dr;
    }
    const int e1 = off[r + 1];
    for (int e = off[r]; e < e1; e++) {
        int s = srcs[e];
        float w = dinv[s];
        uint4 v = ((const uint4*)(x + (size_t)s * K))[lr];
        a[0] = fmaf(bflo(v.x), w, a[0]); a[1] = fmaf(bfhi(v.x), w, a[1]);
        a[2] = fmaf(bflo(v.y), w, a[2]); a[3] = fmaf(bfhi(v.y), w, a[3]);
        a[4] = fmaf(bflo(v.z), w, a[4]); a[5] = fmaf(bfhi(v.z), w, a[5]);
        a[6] = fmaf(bflo(v.w), w, a[6]); a[7] = fmaf(bfhi(v.w), w, a[7]);
    }
    uint4 o;
    o.x = (uint_t)f2bf(a[0] * dr) | ((uint_t)f2bf(a[1] * dr) << 16);
    o.y = (uint_t)f2bf(a[2] * dr) | ((uint_t)f2bf(a[3] * dr) << 16);
    o.z = (uint_t)f2bf(a[4] * dr) | ((uint_t)f2bf(a[5] * dr) << 16);
    o.w = (uint_t)f2bf(a[6] * dr) | ((uint_t)f2bf(a[7] * dr) << 16);
    ((uint4*)(ax + (size_t)r * K))[lr] = o;
}

// ---------------- MFMA GEMM: C[M x 512] = A[M x K](bf16) @ Wt[512 x K]^T + bias, bf16 out ----
// 128x128 tile, BK=32, 4 waves, each wave 64x64 (4x4 frags of 16x16x32)

__global__ __launch_bounds__(256) void gemm_mfma(
        const ushort_t* __restrict__ A, const ushort_t* __restrict__ Wt,
        const float* __restrict__ bias, ushort_t* __restrict__ C, int M, int K) {
    __shared__ __align__(16) ushort_t As[128][40];   // stride 80 B: 16B-aligned, even bank spread
    __shared__ __align__(16) ushort_t Bs[128][40];
    const int t = threadIdx.x;
    const int wave = t >> 6, lane = t & 63;
    const int m0 = blockIdx.y * 128, n0 = blockIdx.x * 128;
    const int wm = (wave & 1) * 64, wn = (wave >> 1) * 64;
    const int quad = lane >> 4, l16 = lane & 15;
    const int sr = t >> 2;              // staging row 0..63
    const int skb = (t & 3) * 8;        // staging k offset

    f32x4 acc[4][4];
#pragma unroll
    for (int i = 0; i < 4; i++)
#pragma unroll
        for (int j = 0; j < 4; j++) acc[i][j] = (f32x4){0.f, 0.f, 0.f, 0.f};

    for (int k0 = 0; k0 < K; k0 += 32) {
#pragma unroll
        for (int j = 0; j < 2; j++) {
            int row = sr + j * 64;
            int gm = m0 + row; if (gm > M - 1) gm = M - 1;
            uint4 av = *(const uint4*)(A + (size_t)gm * K + k0 + skb);
            *(uint4*)&As[row][skb] = av;
            uint4 bv = *(const uint4*)(Wt + (size_t)(n0 + row) * K + k0 + skb);
            *(uint4*)&Bs[row][skb] = bv;
        }
        __syncthreads();
        bf16x8 af[4], bfr[4];
#pragma unroll
        for (int i = 0; i < 4; i++) {
            af[i]  = *(const bf16x8*)&As[wm + i * 16 + l16][quad * 8];
            bfr[i] = *(const bf16x8*)&Bs[wn + i * 16 + l16][quad * 8];
        }
#pragma unroll
        for (int i = 0; i < 4; i++)
#pragma unroll
            for (int jn = 0; jn < 4; jn++)
                acc[i][jn] = __builtin_amdgcn_mfma_f32_16x16x32_bf16(
                                 af[i], bfr[jn], acc[i][jn], 0, 0, 0);
        __syncthreads();
    }
    // epilogue: + bias, pack bf16. D: col = lane&15, row = quad*4 + reg
#pragma unroll
    for (int i = 0; i < 4; i++) {
#pragma unroll
        for (int jn = 0; jn < 4; jn++) {
            int gn = n0 + wn + jn * 16 + l16;
            float bv = bias[gn];
#pragma unroll
            for (int rg = 0; rg < 4; rg++) {
                int gm = m0 + wm + i * 16 + quad * 4 + rg;
                if (gm < M) C[(size_t)gm * HID + gn] = f2bf(acc[i][jn][rg] + bv);
            }
        }
    }
}

// ---------------- LayerNorm + ReLU: bf16 in -> bf16 out, wave per row ----------------

__global__ void ln_relu_bf16(const ushort_t* __restrict__ h, const float* __restrict__ gamma,
                             const float* __restrict__ beta, ushort_t* __restrict__ o, int N) {
    int gtid = blockIdx.x * blockDim.x + threadIdx.x;
    int r = gtid >> 6, lane = gtid & 63;
    if (r >= N) return;
    uint4 v = ((const uint4*)(h + (size_t)r * HID))[lane];   // cols 8*lane .. 8*lane+7
    float f[8] = {bflo(v.x), bfhi(v.x), bflo(v.y), bfhi(v.y),
                  bflo(v.z), bfhi(v.z), bflo(v.w), bfhi(v.w)};
    float s = 0.f, q = 0.f;
#pragma unroll
    for (int j = 0; j < 8; j++) { s += f[j]; q += f[j] * f[j]; }
#pragma unroll
    for (int ofs = 32; ofs > 0; ofs >>= 1) {
        s += __shfl_xor(s, ofs);
        q += __shfl_xor(q, ofs);
    }
    float mu  = s * (1.0f / HID);
    float var = q * (1.0f / HID) - mu * mu;
    float rs  = rsqrtf(var + EPSV);
    const float4* gp = (const float4*)gamma;
    const float4* bp = (const float4*)beta;
    float4 g0 = gp[2 * lane], g1 = gp[2 * lane + 1];
    float4 b0 = bp[2 * lane], b1 = bp[2 * lane + 1];
    float gg[8] = {g0.x, g0.y, g0.z, g0.w, g1.x, g1.y, g1.z, g1.w};
    float bb[8] = {b0.x, b0.y, b0.z, b0.w, b1.x, b1.y, b1.z, b1.w};
    uint_t pk[4];
#pragma unroll
    for (int j = 0; j < 4; j++) {
        float r0 = fmaxf((f[2*j]   - mu) * rs * gg[2*j]   + bb[2*j],   0.f);
        float r1 = fmaxf((f[2*j+1] - mu) * rs * gg[2*j+1] + bb[2*j+1], 0.f);
        pk[j] = (uint_t)f2bf(r0) | ((uint_t)f2bf(r1) << 16);
    }
    uint4 ov; ov.x = pk[0]; ov.y = pk[1]; ov.z = pk[2]; ov.w = pk[3];
    ((uint4*)(o + (size_t)r * HID))[lane] = ov;
}

// ---------------- mean pool + output head ----------------

__global__ void colsum(const ushort_t* __restrict__ h, float* __restrict__ gsum, int N) {
    int t = threadIdx.x;   // 256 -> 2 cols each
    float a0 = 0.f, a1 = 0.f;
    for (int r = blockIdx.x; r < N; r += gridDim.x) {
        uint_t u = ((const uint_t*)(h + (size_t)r * HID))[t];
        a0 += bflo(u);
        a1 += bfhi(u);
    }
    atomicAdd(&gsum[2 * t], a0);
    atomicAdd(&gsum[2 * t + 1], a1);
}

__global__ void out_kernel(const float* __restrict__ gsum, const float* __restrict__ Wout,
                           const float* __restrict__ bout, float* __restrict__ out, int N) {
    __shared__ float red[256];
    int t = threadIdx.x;
    float g0 = gsum[2 * t], g1 = gsum[2 * t + 1];
    float invn = 1.0f / (float)N;
    for (int o = 0; o < OUTD; o++) {
        float p = g0 * Wout[(2 * t) * OUTD + o] + g1 * Wout[(2 * t + 1) * OUTD + o];
        red[t] = p;
        __syncthreads();
        for (int sft = 128; sft > 0; sft >>= 1) {
            if (t < sft) red[t] += red[t + sft];
            __syncthreads();
        }
        if (t == 0) out[o] = red[0] * invn + bout[o];
        __syncthreads();
    }
}

// ---------------- launch ----------------

extern "C" void kernel_launch(void* const* d_in, const int* in_sizes, int n_in,
                              void* d_out, int out_size, void* d_ws, size_t ws_size,
                              hipStream_t stream) {
    const float* x  = (const float*)d_in[0];
    const int*   ei = (const int*)d_in[1];
    const int N = in_sizes[0] / 128;
    const int E = in_sizes[1] / 2;
    const int* src = ei;
    const int* dst = ei + E;
    const float* Ws[4] = {(const float*)d_in[2], (const float*)d_in[4],
                          (const float*)d_in[6], (const float*)d_in[8]};
    const float* bs[4] = {(const float*)d_in[3], (const float*)d_in[5],
                          (const float*)d_in[7], (const float*)d_in[9]};
    const float* gamma = (const float*)d_in[10];
    const float* beta  = (const float*)d_in[11];
    const float* Wout  = (const float*)d_in[12];
    const float* bout  = (const float*)d_in[13];
    float* out = (float*)d_out;

    // workspace layout (16B-aligned chunks first)
    char* p = (char*)d_ws;
    ushort_t* axb = (ushort_t*)p;  p += sizeof(ushort_t) * (size_t)N * HID;   // agg out / gemm A
    ushort_t* hb  = (ushort_t*)p;  p += sizeof(ushort_t) * (size_t)N * HID;   // gemm out (pre-LN)
    ushort_t* ho  = (ushort_t*)p;  p += sizeof(ushort_t) * (size_t)N * HID;   // LN out (layer input)
    ushort_t* xb  = ho;            // alias: x-bf16 (N*128) lives in ho until ln(l1) writes it
    ushort_t* Wt[4];
    Wt[0] = (ushort_t*)p;          p += sizeof(ushort_t) * 128 * HID;
    Wt[1] = (ushort_t*)p;          p += sizeof(ushort_t) * HID * HID;
    Wt[2] = (ushort_t*)p;          p += sizeof(ushort_t) * HID * HID;
    Wt[3] = (ushort_t*)p;          p += sizeof(ushort_t) * HID * HID;
    float* dinv = (float*)p;       p += sizeof(float) * N;
    float* gsum = (float*)p;       p += sizeof(float) * HID;
    int* deg    = (int*)p;         p += sizeof(int) * N;
    int* off    = (int*)p;         p += sizeof(int) * (N + 4);
    int* cursor = (int*)p;         p += sizeof(int) * N;
    int* srcs   = (int*)p;         // E ints

    // ---- CSR build + conversions (once) ----
    zero_init<<<(N + 255) / 256, 256, 0, stream>>>(deg, gsum, N);
    deg_count<<<(E + 255) / 256, 256, 0, stream>>>(dst, deg, E);
    scan_kernel<<<1, SCAN_T, 0, stream>>>(deg, off, cursor, N);
    dinv_kernel<<<(N + 255) / 256, 256, 0, stream>>>(deg, dinv, N);
    fill_csr<<<(E + 255) / 256, 256, 0, stream>>>(src, dst, cursor, srcs, E);
    cvt_x_bf16<<<(N * 128 + 255) / 256, 256, 0, stream>>>(x, xb, N * 128);
    cvt_w_bf16<<<(128 * HID + 255) / 256, 256, 0, stream>>>(Ws[0], Wt[0], 128);
    for (int l = 1; l < 4; l++)
        cvt_w_bf16<<<(HID * HID + 255) / 256, 256, 0, stream>>>(Ws[l], Wt[l], HID);

    for (int l = 0; l < 4; l++) {
        const int K = (l == 0) ? 128 : HID;
        const ushort_t* xin = (l == 0) ? xb : ho;
        if (l == 0)
            csr_agg_bf16<4><<<(N * 16 + 255) / 256, 256, 0, stream>>>(xin, off, srcs, dinv, axb, N);
        else
            csr_agg_bf16<6><<<(N * 64 + 255) / 256, 256, 0, stream>>>(xin, off, srcs, dinv, axb, N);
        dim3 gg(HID / 128, (N + 127) / 128);
        gemm_mfma<<<gg, 256, 0, stream>>>(axb, Wt[l], bs[l], hb, N, K);
        ln_relu_bf16<<<(N * 64 + 255) / 256, 256, 0, stream>>>(hb, gamma, beta, ho, N);
    }
    colsum<<<512, 256, 0, stream>>>(ho, gsum, N);
    out_kernel<<<1, 256, 0, stream>>>(gsum, Wout, bout, out, N);
}

// Round 4
// 518.909 us; speedup vs baseline: 14.7229x; 1.0169x over previous
//
#include <hip/hip_runtime.h>

#define HID 512
#define OUTD 7
#define EPSV 1e-5f
#define SCAN_T 1024

typedef __attribute__((ext_vector_type(8))) short bf16x8;
typedef __attribute__((ext_vector_type(4))) float f32x4;
typedef unsigned short ushort_t;
typedef unsigned int uint_t;

// ---------------- bf16 helpers ----------------
__device__ __forceinline__ ushort_t f2bf(float f) {
    uint_t u = __float_as_uint(f);
    u = (u + 0x7fffu + ((u >> 16) & 1u)) >> 16;    // RNE
    return (ushort_t)u;
}
__device__ __forceinline__ float bflo(uint_t u) { return __uint_as_float(u << 16); }
__device__ __forceinline__ float bfhi(uint_t u) { return __uint_as_float(u & 0xffff0000u); }

// async global->LDS, 16B per lane; LDS dest must be wave-uniform base (lane*16 implicit)
__device__ __forceinline__ void gload_lds16(const ushort_t* g, ushort_t* l) {
    __builtin_amdgcn_global_load_lds(
        (const __attribute__((address_space(1))) uint_t*)g,
        (__attribute__((address_space(3))) uint_t*)l, 16, 0, 0);
}

// ---------------- setup: degree, dinv, CSR ----------------

__global__ void zero_init(int* __restrict__ deg, float* __restrict__ gsum, int N) {
    int i = blockIdx.x * blockDim.x + threadIdx.x;
    if (i < N) deg[i] = 0;
    if (i < HID) gsum[i] = 0.0f;
}

__global__ void deg_count(const int* __restrict__ dst, int* __restrict__ deg, int E) {
    int e = blockIdx.x * blockDim.x + threadIdx.x;
    if (e < E) atomicAdd(&deg[dst[e]], 1);
}

// single-block scan; also computes dinv (fused)
__global__ void scan_kernel(const int* __restrict__ deg, int* __restrict__ off,
                            int* __restrict__ cursor, float* __restrict__ dinv, int N) {
    __shared__ int sums[SCAN_T];
    const int t = threadIdx.x;
    const int chunk = (N + SCAN_T - 1) / SCAN_T;
    const int b = t * chunk;
    const int e = min(b + chunk, N);
    int s = 0;
    for (int i = b; i < e; i++) {
        s += deg[i];
        dinv[i] = rsqrtf((float)(deg[i] + 1));   // +1 self loop
    }
    sums[t] = s;
    __syncthreads();
    for (int ofs = 1; ofs < SCAN_T; ofs <<= 1) {
        int v = 0;
        if (t >= ofs) v = sums[t - ofs];
        __syncthreads();
        sums[t] += v;
        __syncthreads();
    }
    int excl = (t == 0) ? 0 : sums[t - 1];
    for (int i = b; i < e; i++) {
        off[i] = excl; cursor[i] = excl; excl += deg[i];
    }
    if (b < N && e == N) off[N] = excl;
}

__global__ void fill_csr(const int* __restrict__ src, const int* __restrict__ dst,
                         int* __restrict__ cursor, int* __restrict__ srcs, int E) {
    int e = blockIdx.x * blockDim.x + threadIdx.x;
    if (e < E) {
        int p = atomicAdd(&cursor[dst[e]], 1);
        srcs[p] = src[e];
    }
}

// ---------------- fp32 -> bf16 conversions ----------------

__global__ void cvt_x_bf16(const float* __restrict__ x, ushort_t* __restrict__ xb, int total) {
    int i = blockIdx.x * blockDim.x + threadIdx.x;
    if (i < total) xb[i] = f2bf(x[i]);
}

// all 4 weight transposes in one launch: W[K][512] -> Wt[512][K] bf16
__global__ void cvt_w_all(const float* __restrict__ W0, const float* __restrict__ W1,
                          const float* __restrict__ W2, const float* __restrict__ W3,
                          ushort_t* __restrict__ T0, ushort_t* __restrict__ T1,
                          ushort_t* __restrict__ T2, ushort_t* __restrict__ T3) {
    int i = blockIdx.x * blockDim.x + threadIdx.x;
    const int S0 = 128 * HID, S1 = HID * HID;
    if (i < S0) {
        int k = i / HID, n = i % HID;
        T0[(size_t)n * 128 + k] = f2bf(W0[i]);
        return;
    }
    i -= S0;
    if (i < S1) { int k = i / HID, n = i % HID; T1[(size_t)n * HID + k] = f2bf(W1[i]); return; }
    i -= S1;
    if (i < S1) { int k = i / HID, n = i % HID; T2[(size_t)n * HID + k] = f2bf(W2[i]); return; }
    i -= S1;
    if (i < S1) { int k = i / HID, n = i % HID; T3[(size_t)n * HID + k] = f2bf(W3[i]); }
}

// ---------------- aggregation (gather via CSR), bf16 in/out, fp32 accum ----------------

__device__ __forceinline__ void acc8(float* a, uint4 v, float w) {
    a[0] = fmaf(bflo(v.x), w, a[0]); a[1] = fmaf(bfhi(v.x), w, a[1]);
    a[2] = fmaf(bflo(v.y), w, a[2]); a[3] = fmaf(bfhi(v.y), w, a[3]);
    a[4] = fmaf(bflo(v.z), w, a[4]); a[5] = fmaf(bfhi(v.z), w, a[5]);
    a[6] = fmaf(bflo(v.w), w, a[6]); a[7] = fmaf(bfhi(v.w), w, a[7]);
}

// LPRS: log2(lanes per row). K = (1<<LPRS)*8. Each lane holds one uint4 (8 bf16).
// Edge loop unrolled x4: 4 independent gathers in flight per wave (latency hiding).
template<int LPRS>
__global__ void csr_agg_bf16(const ushort_t* __restrict__ x, const int* __restrict__ off,
                             const int* __restrict__ srcs, const float* __restrict__ dinv,
                             ushort_t* __restrict__ ax, int N) {
    const int LPR = 1 << LPRS;
    const int K = LPR * 8;
    int gtid = blockIdx.x * blockDim.x + threadIdx.x;
    int wave = gtid >> 6, lane = gtid & 63;
    int sub = lane >> LPRS;
    int lr = lane & (LPR - 1);
    int r = wave * (64 >> LPRS) + sub;
    if (r >= N) return;
    const float dr = dinv[r];
    float a[8];
    {
        uint4 v = ((const uint4*)(x + (size_t)r * K))[lr];
        a[0] = bflo(v.x) * dr; a[1] = bfhi(v.x) * dr;
        a[2] = bflo(v.y) * dr; a[3] = bfhi(v.y) * dr;
        a[4] = bflo(v.z) * dr; a[5] = bfhi(v.z) * dr;
        a[6] = bflo(v.w) * dr; a[7] = bfhi(v.w) * dr;
    }
    int e = off[r];
    const int e1 = off[r + 1];
    for (; e + 4 <= e1; e += 4) {
        int s0 = srcs[e], s1 = srcs[e + 1], s2 = srcs[e + 2], s3 = srcs[e + 3];
        float w0 = dinv[s0], w1 = dinv[s1], w2 = dinv[s2], w3 = dinv[s3];
        uint4 v0 = ((const uint4*)(x + (size_t)s0 * K))[lr];
        uint4 v1 = ((const uint4*)(x + (size_t)s1 * K))[lr];
        uint4 v2 = ((const uint4*)(x + (size_t)s2 * K))[lr];
        uint4 v3 = ((const uint4*)(x + (size_t)s3 * K))[lr];
        acc8(a, v0, w0); acc8(a, v1, w1); acc8(a, v2, w2); acc8(a, v3, w3);
    }
    for (; e < e1; e++) {
        int s = srcs[e];
        float w = dinv[s];
        uint4 v = ((const uint4*)(x + (size_t)s * K))[lr];
        acc8(a, v, w);
    }
    uint4 o;
    o.x = (uint_t)f2bf(a[0] * dr) | ((uint_t)f2bf(a[1] * dr) << 16);
    o.y = (uint_t)f2bf(a[2] * dr) | ((uint_t)f2bf(a[3] * dr) << 16);
    o.z = (uint_t)f2bf(a[4] * dr) | ((uint_t)f2bf(a[5] * dr) << 16);
    o.w = (uint_t)f2bf(a[6] * dr) | ((uint_t)f2bf(a[7] * dr) << 16);
    ((uint4*)(ax + (size_t)r * K))[lr] = o;
}

// ---------------- MFMA GEMM: C[M x 512] = A[M x K](bf16) @ Wt[512 x K]^T + bias, bf16 out ----
// 128x128 tile, BK=32, 4 waves (64x64 each, 4x4 frags of 16x16x32).
// LDS tiles chunk-major [chunk 0..3][row 0..127][8 bf16] — global_load_lds-compatible
// (contiguous in lane order) and conflict-free for ds_read_b128 (lane stride 16B).

__global__ __launch_bounds__(256) void gemm_mfma(
        const ushort_t* __restrict__ A, const ushort_t* __restrict__ Wt,
        const float* __restrict__ bias, ushort_t* __restrict__ C, int M, int K) {
    __shared__ __align__(16) ushort_t As[4 * 128 * 8];   // 8 KB
    __shared__ __align__(16) ushort_t Bs[4 * 128 * 8];   // 8 KB
    const int t = threadIdx.x;
    const int wave = t >> 6, lane = t & 63;
    const int m0 = blockIdx.y * 128, n0 = blockIdx.x * 128;
    const int wm = (wave & 1) * 64, wn = (wave >> 1) * 64;
    const int quad = lane >> 4, l16 = lane & 15;

    f32x4 acc[4][4];
#pragma unroll
    for (int i = 0; i < 4; i++)
#pragma unroll
        for (int j = 0; j < 4; j++) acc[i][j] = (f32x4){0.f, 0.f, 0.f, 0.f};

    for (int k0 = 0; k0 < K; k0 += 32) {
        const int c = wave;   // wave stages its own k-chunk
#pragma unroll
        for (int h = 0; h < 2; h++) {
            int gm = m0 + 64 * h + lane;
            if (gm >= M) gm = M - 1;
            gload_lds16(A + (size_t)gm * K + k0 + c * 8, &As[(c * 128 + 64 * h) * 8]);
            gload_lds16(Wt + (size_t)(n0 + 64 * h + lane) * K + k0 + c * 8,
                        &Bs[(c * 128 + 64 * h) * 8]);
        }
        __syncthreads();
        bf16x8 af[4], bfr[4];
#pragma unroll
        for (int i = 0; i < 4; i++) {
            af[i]  = *(const bf16x8*)&As[(quad * 128 + wm + i * 16 + l16) * 8];
            bfr[i] = *(const bf16x8*)&Bs[(quad * 128 + wn + i * 16 + l16) * 8];
        }
#pragma unroll
        for (int i = 0; i < 4; i++)
#pragma unroll
            for (int jn = 0; jn < 4; jn++)
                acc[i][jn] = __builtin_amdgcn_mfma_f32_16x16x32_bf16(
                                 af[i], bfr[jn], acc[i][jn], 0, 0, 0);
        __syncthreads();
    }
    // epilogue: + bias, pack bf16. D: col = lane&15, row = quad*4 + reg
#pragma unroll
    for (int i = 0; i < 4; i++) {
#pragma unroll
        for (int jn = 0; jn < 4; jn++) {
            int gn = n0 + wn + jn * 16 + l16;
            float bv = bias[gn];
#pragma unroll
            for (int rg = 0; rg < 4; rg++) {
                int gm = m0 + wm + i * 16 + quad * 4 + rg;
                if (gm < M) C[(size_t)gm * HID + gn] = f2bf(acc[i][jn][rg] + bv);
            }
        }
    }
}

// ---------------- LayerNorm + ReLU: bf16 in -> bf16 out, wave per row ----------------

__global__ void ln_relu_bf16(const ushort_t* __restrict__ h, const float* __restrict__ gamma,
                             const float* __restrict__ beta, ushort_t* __restrict__ o, int N) {
    int gtid = blockIdx.x * blockDim.x + threadIdx.x;
    int r = gtid >> 6, lane = gtid & 63;
    if (r >= N) return;
    uint4 v = ((const uint4*)(h + (size_t)r * HID))[lane];
    float f[8] = {bflo(v.x), bfhi(v.x), bflo(v.y), bfhi(v.y),
                  bflo(v.z), bfhi(v.z), bflo(v.w), bfhi(v.w)};
    float s = 0.f, q = 0.f;
#pragma unroll
    for (int j = 0; j < 8; j++) { s += f[j]; q += f[j] * f[j]; }
#pragma unroll
    for (int ofs = 32; ofs > 0; ofs >>= 1) {
        s += __shfl_xor(s, ofs);
        q += __shfl_xor(q, ofs);
    }
    float mu  = s * (1.0f / HID);
    float var = q * (1.0f / HID) - mu * mu;
    float rs  = rsqrtf(var + EPSV);
    const float4* gp = (const float4*)gamma;
    const float4* bp = (const float4*)beta;
    float4 g0 = gp[2 * lane], g1 = gp[2 * lane + 1];
    float4 b0 = bp[2 * lane], b1 = bp[2 * lane + 1];
    float gg[8] = {g0.x, g0.y, g0.z, g0.w, g1.x, g1.y, g1.z, g1.w};
    float bb[8] = {b0.x, b0.y, b0.z, b0.w, b1.x, b1.y, b1.z, b1.w};
    uint_t pk[4];
#pragma unroll
    for (int j = 0; j < 4; j++) {
        float r0 = fmaxf((f[2*j]   - mu) * rs * gg[2*j]   + bb[2*j],   0.f);
        float r1 = fmaxf((f[2*j+1] - mu) * rs * gg[2*j+1] + bb[2*j+1], 0.f);
        pk[j] = (uint_t)f2bf(r0) | ((uint_t)f2bf(r1) << 16);
    }
    uint4 ov; ov.x = pk[0]; ov.y = pk[1]; ov.z = pk[2]; ov.w = pk[3];
    ((uint4*)(o + (size_t)r * HID))[lane] = ov;
}

// ---------------- mean pool + output head ----------------

__global__ void colsum(const ushort_t* __restrict__ h, float* __restrict__ gsum, int N) {
    int t = threadIdx.x;   // 256 -> 2 cols each
    float a0 = 0.f, a1 = 0.f;
    for (int r = blockIdx.x; r < N; r += gridDim.x) {
        uint_t u = ((const uint_t*)(h + (size_t)r * HID))[t];
        a0 += bflo(u);
        a1 += bfhi(u);
    }
    atomicAdd(&gsum[2 * t], a0);
    atomicAdd(&gsum[2 * t + 1], a1);
}

__global__ void out_kernel(const float* __restrict__ gsum, const float* __restrict__ Wout,
                           const float* __restrict__ bout, float* __restrict__ out, int N) {
    __shared__ float red[256];
    int t = threadIdx.x;
    float g0 = gsum[2 * t], g1 = gsum[2 * t + 1];
    float invn = 1.0f / (float)N;
    for (int o = 0; o < OUTD; o++) {
        float p = g0 * Wout[(2 * t) * OUTD + o] + g1 * Wout[(2 * t + 1) * OUTD + o];
        red[t] = p;
        __syncthreads();
        for (int sft = 128; sft > 0; sft >>= 1) {
            if (t < sft) red[t] += red[t + sft];
            __syncthreads();
        }
        if (t == 0) out[o] = red[0] * invn + bout[o];
        __syncthreads();
    }
}

// ---------------- launch ----------------

extern "C" void kernel_launch(void* const* d_in, const int* in_sizes, int n_in,
                              void* d_out, int out_size, void* d_ws, size_t ws_size,
                              hipStream_t stream) {
    const float* x  = (const float*)d_in[0];
    const int*   ei = (const int*)d_in[1];
    const int N = in_sizes[0] / 128;
    const int E = in_sizes[1] / 2;
    const int* src = ei;
    const int* dst = ei + E;
    const float* Ws[4] = {(const float*)d_in[2], (const float*)d_in[4],
                          (const float*)d_in[6], (const float*)d_in[8]};
    const float* bs[4] = {(const float*)d_in[3], (const float*)d_in[5],
                          (const float*)d_in[7], (const float*)d_in[9]};
    const float* gamma = (const float*)d_in[10];
    const float* beta  = (const float*)d_in[11];
    const float* Wout  = (const float*)d_in[12];
    const float* bout  = (const float*)d_in[13];
    float* out = (float*)d_out;

    // workspace layout (16B-aligned chunks first)
    char* p = (char*)d_ws;
    ushort_t* axb = (ushort_t*)p;  p += sizeof(ushort_t) * (size_t)N * HID;   // agg out / gemm A
    ushort_t* hb  = (ushort_t*)p;  p += sizeof(ushort_t) * (size_t)N * HID;   // gemm out (pre-LN)
    ushort_t* ho  = (ushort_t*)p;  p += sizeof(ushort_t) * (size_t)N * HID;   // LN out (layer input)
    ushort_t* xb  = ho;            // alias: x-bf16 (N*128) lives in ho until ln(l0) writes it
    ushort_t* Wt[4];
    Wt[0] = (ushort_t*)p;          p += sizeof(ushort_t) * 128 * HID;
    Wt[1] = (ushort_t*)p;          p += sizeof(ushort_t) * HID * HID;
    Wt[2] = (ushort_t*)p;          p += sizeof(ushort_t) * HID * HID;
    Wt[3] = (ushort_t*)p;          p += sizeof(ushort_t) * HID * HID;
    float* dinv = (float*)p;       p += sizeof(float) * N;
    float* gsum = (float*)p;       p += sizeof(float) * HID;
    int* deg    = (int*)p;         p += sizeof(int) * N;
    int* off    = (int*)p;         p += sizeof(int) * (N + 4);
    int* cursor = (int*)p;         p += sizeof(int) * N;
    int* srcs   = (int*)p;         // E ints

    // ---- CSR build + conversions (once) ----
    zero_init<<<(N + 255) / 256, 256, 0, stream>>>(deg, gsum, N);
    deg_count<<<(E + 255) / 256, 256, 0, stream>>>(dst, deg, E);
    scan_kernel<<<1, SCAN_T, 0, stream>>>(deg, off, cursor, dinv, N);
    fill_csr<<<(E + 255) / 256, 256, 0, stream>>>(src, dst, cursor, srcs, E);
    cvt_x_bf16<<<(N * 128 + 255) / 256, 256, 0, stream>>>(x, xb, N * 128);
    {
        int tot = 128 * HID + 3 * HID * HID;
        cvt_w_all<<<(tot + 255) / 256, 256, 0, stream>>>(Ws[0], Ws[1], Ws[2], Ws[3],
                                                         Wt[0], Wt[1], Wt[2], Wt[3]);
    }

    for (int l = 0; l < 4; l++) {
        const int K = (l == 0) ? 128 : HID;
        const ushort_t* xin = (l == 0) ? xb : ho;
        if (l == 0)
            csr_agg_bf16<4><<<(N * 16 + 255) / 256, 256, 0, stream>>>(xin, off, srcs, dinv, axb, N);
        else
            csr_agg_bf16<6><<<(N * 64 + 255) / 256, 256, 0, stream>>>(xin, off, srcs, dinv, axb, N);
        dim3 gg(HID / 128, (N + 127) / 128);
        gemm_mfma<<<gg, 256, 0, stream>>>(axb, Wt[l], bs[l], hb, N, K);
        ln_relu_bf16<<<(N * 64 + 255) / 256, 256, 0, stream>>>(hb, gamma, beta, ho, N);
    }
    colsum<<<512, 256, 0, stream>>>(ho, gsum, N);
    out_kernel<<<1, 256, 0, stream>>>(gsum, Wout, bout, out, N);
}

// Round 5
// 475.285 us; speedup vs baseline: 16.0743x; 1.0918x over previous
//
#include <hip/hip_runtime.h>

#define HID 512
#define OUTD 7
#define EPSV 1e-5f

typedef __attribute__((ext_vector_type(8))) short bf16x8;
typedef __attribute__((ext_vector_type(4))) float f32x4;
typedef unsigned short ushort_t;
typedef unsigned int uint_t;

// ---------------- bf16 helpers ----------------
__device__ __forceinline__ ushort_t f2bf(float f) {
    uint_t u = __float_as_uint(f);
    u = (u + 0x7fffu + ((u >> 16) & 1u)) >> 16;    // RNE
    return (ushort_t)u;
}
__device__ __forceinline__ float bflo(uint_t u) { return __uint_as_float(u << 16); }
__device__ __forceinline__ float bfhi(uint_t u) { return __uint_as_float(u & 0xffff0000u); }

// async global->LDS, 16B per lane; LDS dest is wave-uniform base + lane*16
__device__ __forceinline__ void gload_lds16(const ushort_t* g, ushort_t* l) {
    __builtin_amdgcn_global_load_lds(
        (const __attribute__((address_space(1))) uint_t*)g,
        (__attribute__((address_space(3))) uint_t*)l, 16, 0, 0);
}

// ---------------- fused setup 1: zero deg/gsum + x -> bf16 ----------------

__global__ void setup1(const float* __restrict__ x, ushort_t* __restrict__ xb, int totalx,
                       int* __restrict__ deg, float* __restrict__ gsum, int N) {
    int i = blockIdx.x * blockDim.x + threadIdx.x;
    if (i < totalx) xb[i] = f2bf(x[i]);
    if (i < N) deg[i] = 0;
    if (i < HID) gsum[i] = 0.0f;
}

// ---------------- fused setup 2: degree count + all weight transposes ----------------

__global__ void setup2(const int* __restrict__ dst, int* __restrict__ deg, int E,
                       const float* __restrict__ W0, const float* __restrict__ W1,
                       const float* __restrict__ W2, const float* __restrict__ W3,
                       ushort_t* __restrict__ T0, ushort_t* __restrict__ T1,
                       ushort_t* __restrict__ T2, ushort_t* __restrict__ T3) {
    int i = blockIdx.x * blockDim.x + threadIdx.x;
    if (i < E) { atomicAdd(&deg[dst[i]], 1); return; }
    i -= E;
    const int S0 = 128 * HID, S1 = HID * HID;
    if (i < S0) { int k = i / HID, n = i % HID; T0[(size_t)n * 128 + k] = f2bf(W0[i]); return; }
    i -= S0;
    if (i < S1) { int k = i / HID, n = i % HID; T1[(size_t)n * HID + k] = f2bf(W1[i]); return; }
    i -= S1;
    if (i < S1) { int k = i / HID, n = i % HID; T2[(size_t)n * HID + k] = f2bf(W2[i]); return; }
    i -= S1;
    if (i < S1) { int k = i / HID, n = i % HID; T3[(size_t)n * HID + k] = f2bf(W3[i]); }
}

// ---------------- hierarchical scan (3 phases) ----------------
// scan1: per-256-node block: local exclusive scan -> off, block total -> partial; dinv fused
__global__ void scan1(const int* __restrict__ deg, int* __restrict__ off,
                      int* __restrict__ partial, float* __restrict__ dinv, int N) {
    __shared__ int s[256];
    const int t = threadIdx.x;
    const int i = blockIdx.x * 256 + t;
    int d = (i < N) ? deg[i] : 0;
    if (i < N) dinv[i] = rsqrtf((float)(d + 1));   // +1 self loop
    s[t] = d;
    __syncthreads();
#pragma unroll
    for (int ofs = 1; ofs < 256; ofs <<= 1) {
        int v = (t >= ofs) ? s[t - ofs] : 0;
        __syncthreads();
        s[t] += v;
        __syncthreads();
    }
    if (i < N) off[i] = s[t] - d;                  // local exclusive
    if (t == 255) partial[blockIdx.x] = s[255];    // block total
}

// scan2: single block, exclusive scan of <=256 partials (in place)
__global__ void scan2(int* __restrict__ partial, int nb) {
    __shared__ int s[256];
    const int t = threadIdx.x;
    int d = (t < nb) ? partial[t] : 0;
    s[t] = d;
    __syncthreads();
#pragma unroll
    for (int ofs = 1; ofs < 256; ofs <<= 1) {
        int v = (t >= ofs) ? s[t - ofs] : 0;
        __syncthreads();
        s[t] += v;
        __syncthreads();
    }
    if (t < nb) partial[t] = s[t] - d;             // exclusive block offsets
}

// scan3: add block offsets; produce cursor copy; off[N] = E
__global__ void scan3(int* __restrict__ off, const int* __restrict__ partial,
                      int* __restrict__ cursor, int N, int E) {
    int i = blockIdx.x * blockDim.x + threadIdx.x;
    if (i < N) {
        int v = off[i] + partial[i >> 8];
        off[i] = v;
        cursor[i] = v;
    } else if (i == N) {
        off[N] = E;
    }
}

__global__ void fill_csr(const int* __restrict__ src, const int* __restrict__ dst,
                         int* __restrict__ cursor, int* __restrict__ srcs, int E) {
    int e = blockIdx.x * blockDim.x + threadIdx.x;
    if (e < E) {
        int p = atomicAdd(&cursor[dst[e]], 1);
        srcs[p] = src[e];
    }
}

// ---------------- aggregation (gather via CSR), bf16 in/out, fp32 accum ----------------

__device__ __forceinline__ void acc8(float* a, uint4 v, float w) {
    a[0] = fmaf(bflo(v.x), w, a[0]); a[1] = fmaf(bfhi(v.x), w, a[1]);
    a[2] = fmaf(bflo(v.y), w, a[2]); a[3] = fmaf(bfhi(v.y), w, a[3]);
    a[4] = fmaf(bflo(v.z), w, a[4]); a[5] = fmaf(bfhi(v.z), w, a[5]);
    a[6] = fmaf(bflo(v.w), w, a[6]); a[7] = fmaf(bfhi(v.w), w, a[7]);
}

// LPRS: log2(lanes per row). K = (1<<LPRS)*8. Each lane holds one uint4 (8 bf16).
// Edge loop unrolled x8: 8 independent row-gathers (8 KB/wave) in flight.
template<int LPRS>
__global__ void csr_agg_bf16(const ushort_t* __restrict__ x, const int* __restrict__ off,
                             const int* __restrict__ srcs, const float* __restrict__ dinv,
                             ushort_t* __restrict__ ax, int N) {
    const int LPR = 1 << LPRS;
    const int K = LPR * 8;
    int gtid = blockIdx.x * blockDim.x + threadIdx.x;
    int wave = gtid >> 6, lane = gtid & 63;
    int sub = lane >> LPRS;
    int lr = lane & (LPR - 1);
    int r = wave * (64 >> LPRS) + sub;
    if (r >= N) return;
    const float dr = dinv[r];
    float a[8];
    {
        uint4 v = ((const uint4*)(x + (size_t)r * K))[lr];
        a[0] = bflo(v.x) * dr; a[1] = bfhi(v.x) * dr;
        a[2] = bflo(v.y) * dr; a[3] = bfhi(v.y) * dr;
        a[4] = bflo(v.z) * dr; a[5] = bfhi(v.z) * dr;
        a[6] = bflo(v.w) * dr; a[7] = bfhi(v.w) * dr;
    }
    int e = off[r];
    const int e1 = off[r + 1];
    for (; e + 8 <= e1; e += 8) {
        int   si[8]; float wi[8]; uint4 vi[8];
#pragma unroll
        for (int j = 0; j < 8; j++) si[j] = srcs[e + j];
#pragma unroll
        for (int j = 0; j < 8; j++) wi[j] = dinv[si[j]];
#pragma unroll
        for (int j = 0; j < 8; j++) vi[j] = ((const uint4*)(x + (size_t)si[j] * K))[lr];
#pragma unroll
        for (int j = 0; j < 8; j++) acc8(a, vi[j], wi[j]);
    }
    for (; e + 4 <= e1; e += 4) {
        int   si[4]; float wi[4]; uint4 vi[4];
#pragma unroll
        for (int j = 0; j < 4; j++) si[j] = srcs[e + j];
#pragma unroll
        for (int j = 0; j < 4; j++) wi[j] = dinv[si[j]];
#pragma unroll
        for (int j = 0; j < 4; j++) vi[j] = ((const uint4*)(x + (size_t)si[j] * K))[lr];
#pragma unroll
        for (int j = 0; j < 4; j++) acc8(a, vi[j], wi[j]);
    }
    for (; e < e1; e++) {
        int s = srcs[e];
        float w = dinv[s];
        uint4 v = ((const uint4*)(x + (size_t)s * K))[lr];
        acc8(a, v, w);
    }
    uint4 o;
    o.x = (uint_t)f2bf(a[0] * dr) | ((uint_t)f2bf(a[1] * dr) << 16);
    o.y = (uint_t)f2bf(a[2] * dr) | ((uint_t)f2bf(a[3] * dr) << 16);
    o.z = (uint_t)f2bf(a[4] * dr) | ((uint_t)f2bf(a[5] * dr) << 16);
    o.w = (uint_t)f2bf(a[6] * dr) | ((uint_t)f2bf(a[7] * dr) << 16);
    ((uint4*)(ax + (size_t)r * K))[lr] = o;
}

// ---------------- MFMA GEMM: C[M x 512] = A[M x K](bf16) @ Wt[512 x K]^T + bias, bf16 out ----
// 128x128 tile, BK=32, 4 waves (64x64 each, 4x4 frags of 16x16x32).
// LDS chunk-major [chunk 0..3][row 0..127][8 bf16] — global_load_lds-compatible,
// conflict-free ds_read_b128 (lane stride 16B).

__global__ __launch_bounds__(256) void gemm_mfma(
        const ushort_t* __restrict__ A, const ushort_t* __restrict__ Wt,
        const float* __restrict__ bias, ushort_t* __restrict__ C, int M, int K) {
    __shared__ __align__(16) ushort_t As[4 * 128 * 8];   // 8 KB
    __shared__ __align__(16) ushort_t Bs[4 * 128 * 8];   // 8 KB
    const int t = threadIdx.x;
    const int wave = t >> 6, lane = t & 63;
    const int m0 = blockIdx.y * 128, n0 = blockIdx.x * 128;
    const int wm = (wave & 1) * 64, wn = (wave >> 1) * 64;
    const int quad = lane >> 4, l16 = lane & 15;

    f32x4 acc[4][4];
#pragma unroll
    for (int i = 0; i < 4; i++)
#pragma unroll
        for (int j = 0; j < 4; j++) acc[i][j] = (f32x4){0.f, 0.f, 0.f, 0.f};

    for (int k0 = 0; k0 < K; k0 += 32) {
        const int c = wave;   // wave stages its own k-chunk
#pragma unroll
        for (int h = 0; h < 2; h++) {
            int gm = m0 + 64 * h + lane;
            if (gm >= M) gm = M - 1;
            gload_lds16(A + (size_t)gm * K + k0 + c * 8, &As[(c * 128 + 64 * h) * 8]);
            gload_lds16(Wt + (size_t)(n0 + 64 * h + lane) * K + k0 + c * 8,
                        &Bs[(c * 128 + 64 * h) * 8]);
        }
        __syncthreads();
        bf16x8 af[4], bfr[4];
#pragma unroll
        for (int i = 0; i < 4; i++) {
            af[i]  = *(const bf16x8*)&As[(quad * 128 + wm + i * 16 + l16) * 8];
            bfr[i] = *(const bf16x8*)&Bs[(quad * 128 + wn + i * 16 + l16) * 8];
        }
#pragma unroll
        for (int i = 0; i < 4; i++)
#pragma unroll
            for (int jn = 0; jn < 4; jn++)
                acc[i][jn] = __builtin_amdgcn_mfma_f32_16x16x32_bf16(
                                 af[i], bfr[jn], acc[i][jn], 0, 0, 0);
        __syncthreads();
    }
    // epilogue: + bias, pack bf16. D: col = lane&15, row = quad*4 + reg
#pragma unroll
    for (int i = 0; i < 4; i++) {
#pragma unroll
        for (int jn = 0; jn < 4; jn++) {
            int gn = n0 + wn + jn * 16 + l16;
            float bv = bias[gn];
#pragma unroll
            for (int rg = 0; rg < 4; rg++) {
                int gm = m0 + wm + i * 16 + quad * 4 + rg;
                if (gm < M) C[(size_t)gm * HID + gn] = f2bf(acc[i][jn][rg] + bv);
            }
        }
    }
}

// ---------------- LayerNorm + ReLU: bf16 in -> bf16 out, wave per row ----------------

__global__ void ln_relu_bf16(const ushort_t* __restrict__ h, const float* __restrict__ gamma,
                             const float* __restrict__ beta, ushort_t* __restrict__ o, int N) {
    int gtid = blockIdx.x * blockDim.x + threadIdx.x;
    int r = gtid >> 6, lane = gtid & 63;
    if (r >= N) return;
    uint4 v = ((const uint4*)(h + (size_t)r * HID))[lane];
    float f[8] = {bflo(v.x), bfhi(v.x), bflo(v.y), bfhi(v.y),
                  bflo(v.z), bfhi(v.z), bflo(v.w), bfhi(v.w)};
    float s = 0.f, q = 0.f;
#pragma unroll
    for (int j = 0; j < 8; j++) { s += f[j]; q += f[j] * f[j]; }
#pragma unroll
    for (int ofs = 32; ofs > 0; ofs >>= 1) {
        s += __shfl_xor(s, ofs);
        q += __shfl_xor(q, ofs);
    }
    float mu  = s * (1.0f / HID);
    float var = q * (1.0f / HID) - mu * mu;
    float rs  = rsqrtf(var + EPSV);
    const float4* gp = (const float4*)gamma;
    const float4* bp = (const float4*)beta;
    float4 g0 = gp[2 * lane], g1 = gp[2 * lane + 1];
    float4 b0 = bp[2 * lane], b1 = bp[2 * lane + 1];
    float gg[8] = {g0.x, g0.y, g0.z, g0.w, g1.x, g1.y, g1.z, g1.w};
    float bb[8] = {b0.x, b0.y, b0.z, b0.w, b1.x, b1.y, b1.z, b1.w};
    uint_t pk[4];
#pragma unroll
    for (int j = 0; j < 4; j++) {
        float r0 = fmaxf((f[2*j]   - mu) * rs * gg[2*j]   + bb[2*j],   0.f);
        float r1 = fmaxf((f[2*j+1] - mu) * rs * gg[2*j+1] + bb[2*j+1], 0.f);
        pk[j] = (uint_t)f2bf(r0) | ((uint_t)f2bf(r1) << 16);
    }
    uint4 ov; ov.x = pk[0]; ov.y = pk[1]; ov.z = pk[2]; ov.w = pk[3];
    ((uint4*)(o + (size_t)r * HID))[lane] = ov;
}

// ---------------- mean pool + output head ----------------

__global__ void colsum(const ushort_t* __restrict__ h, float* __restrict__ gsum, int N) {
    int t = threadIdx.x;   // 256 -> 2 cols each
    float a0 = 0.f, a1 = 0.f;
    for (int r = blockIdx.x; r < N; r += gridDim.x) {
        uint_t u = ((const uint_t*)(h + (size_t)r * HID))[t];
        a0 += bflo(u);
        a1 += bfhi(u);
    }
    atomicAdd(&gsum[2 * t], a0);
    atomicAdd(&gsum[2 * t + 1], a1);
}

__global__ void out_kernel(const float* __restrict__ gsum, const float* __restrict__ Wout,
                           const float* __restrict__ bout, float* __restrict__ out, int N) {
    __shared__ float red[256];
    int t = threadIdx.x;
    float g0 = gsum[2 * t], g1 = gsum[2 * t + 1];
    float invn = 1.0f / (float)N;
    for (int o = 0; o < OUTD; o++) {
        float p = g0 * Wout[(2 * t) * OUTD + o] + g1 * Wout[(2 * t + 1) * OUTD + o];
        red[t] = p;
        __syncthreads();
        for (int sft = 128; sft > 0; sft >>= 1) {
            if (t < sft) red[t] += red[t + sft];
            __syncthreads();
        }
        if (t == 0) out[o] = red[0] * invn + bout[o];
        __syncthreads();
    }
}

// ---------------- launch ----------------

extern "C" void kernel_launch(void* const* d_in, const int* in_sizes, int n_in,
                              void* d_out, int out_size, void* d_ws, size_t ws_size,
                              hipStream_t stream) {
    const float* x  = (const float*)d_in[0];
    const int*   ei = (const int*)d_in[1];
    const int N = in_sizes[0] / 128;
    const int E = in_sizes[1] / 2;
    const int* src = ei;
    const int* dst = ei + E;
    const float* Ws[4] = {(const float*)d_in[2], (const float*)d_in[4],
                          (const float*)d_in[6], (const float*)d_in[8]};
    const float* bs[4] = {(const float*)d_in[3], (const float*)d_in[5],
                          (const float*)d_in[7], (const float*)d_in[9]};
    const float* gamma = (const float*)d_in[10];
    const float* beta  = (const float*)d_in[11];
    const float* Wout  = (const float*)d_in[12];
    const float* bout  = (const float*)d_in[13];
    float* out = (float*)d_out;

    // workspace layout (16B-aligned chunks first)
    char* p = (char*)d_ws;
    ushort_t* axb = (ushort_t*)p;  p += sizeof(ushort_t) * (size_t)N * HID;   // agg out / gemm A
    ushort_t* hb  = (ushort_t*)p;  p += sizeof(ushort_t) * (size_t)N * HID;   // gemm out (pre-LN)
    ushort_t* ho  = (ushort_t*)p;  p += sizeof(ushort_t) * (size_t)N * HID;   // LN out (layer input)
    ushort_t* xb  = ho;            // alias: x-bf16 (N*128) lives in ho until ln(l0) writes it
    ushort_t* Wt[4];
    Wt[0] = (ushort_t*)p;          p += sizeof(ushort_t) * 128 * HID;
    Wt[1] = (ushort_t*)p;          p += sizeof(ushort_t) * HID * HID;
    Wt[2] = (ushort_t*)p;          p += sizeof(ushort_t) * HID * HID;
    Wt[3] = (ushort_t*)p;          p += sizeof(ushort_t) * HID * HID;
    float* dinv = (float*)p;       p += sizeof(float) * N;
    float* gsum = (float*)p;       p += sizeof(float) * HID;
    int* deg    = (int*)p;         p += sizeof(int) * N;
    int* off    = (int*)p;         p += sizeof(int) * (N + 4);
    int* cursor = (int*)p;         p += sizeof(int) * N;
    int* partial= (int*)p;         p += sizeof(int) * 256;
    int* srcs   = (int*)p;         // E ints

    const int nb = (N + 255) / 256;   // scan blocks

    // ---- setup: CSR build + conversions (once) ----
    setup1<<<(N * 128 + 255) / 256, 256, 0, stream>>>(x, xb, N * 128, deg, gsum, N);
    {
        int tot = E + 128 * HID + 3 * HID * HID;
        setup2<<<(tot + 255) / 256, 256, 0, stream>>>(dst, deg, E, Ws[0], Ws[1], Ws[2], Ws[3],
                                                      Wt[0], Wt[1], Wt[2], Wt[3]);
    }
    scan1<<<nb, 256, 0, stream>>>(deg, off, partial, dinv, N);
    scan2<<<1, 256, 0, stream>>>(partial, nb);
    scan3<<<(N + 256) / 256, 256, 0, stream>>>(off, partial, cursor, N, E);
    fill_csr<<<(E + 255) / 256, 256, 0, stream>>>(src, dst, cursor, srcs, E);

    for (int l = 0; l < 4; l++) {
        const int K = (l == 0) ? 128 : HID;
        const ushort_t* xin = (l == 0) ? xb : ho;
        if (l == 0)
            csr_agg_bf16<4><<<(N * 16 + 255) / 256, 256, 0, stream>>>(xin, off, srcs, dinv, axb, N);
        else
            csr_agg_bf16<6><<<(N * 64 + 255) / 256, 256, 0, stream>>>(xin, off, srcs, dinv, axb, N);
        dim3 gg(HID / 128, (N + 127) / 128);
        gemm_mfma<<<gg, 256, 0, stream>>>(axb, Wt[l], bs[l], hb, N, K);
        ln_relu_bf16<<<(N * 64 + 255) / 256, 256, 0, stream>>>(hb, gamma, beta, ho, N);
    }
    colsum<<<512, 256, 0, stream>>>(ho, gsum, N);
    out_kernel<<<1, 256, 0, stream>>>(gsum, Wout, bout, out, N);
}